// Round 5
// baseline (694.371 us; speedup 1.0000x reference)
//
#include <hip/hip_runtime.h>

// Problem constants
#define N_NODES 20000
#define N_ATTRS 5000
#define IN_F    512
#define OUT_F   128
#define NK      160           // ksteps of 32 attrs (5120 padded)
#define NSS     80            // supersteps per parity (2 ksteps each)
#define WH2_PAD 5376          // wh2 allocation incl. pad
#define NEGBIG  -1e30f        // wh2 pad: exp2 underflows to 0 -> self-masking tail
#define LOG2E   1.4426950408889634f

// mega-kernel grid partition (pack | wh | attr_h, all independent given prep)
#define PACK_BLOCKS 12500
#define WH_BLOCKS   6250
#define AH_BLOCKS   80

typedef _Float16 f16x8 __attribute__((ext_vector_type(8)));
typedef float    f32x4 __attribute__((ext_vector_type(4)));
typedef int      i32x4 __attribute__((ext_vector_type(4)));

__device__ __forceinline__ float fast_exp2(float x) {
    return __builtin_amdgcn_exp2f(x);
}

// ---------------------------------------------------------------------------
// Kernel 1: Wa1 = W @ a[:128], Wa2 = W @ a[128:], pre-scaled by log2(e);
// repack W into f16 MFMA B-fragment order.
// ---------------------------------------------------------------------------
__global__ __launch_bounds__(256) void prep_kernel(
    const float* __restrict__ W, const float* __restrict__ a,
    float* __restrict__ Wa1, float* __restrict__ Wa2, _Float16* __restrict__ Wp) {
    int gt = blockIdx.x * blockDim.x + threadIdx.x;
    if (gt < IN_F) {
        int k = gt;
        float s1 = 0.f, s2 = 0.f;
        for (int f = 0; f < OUT_F; ++f) {
            float w = W[k * OUT_F + f];
            s1 += w * a[f];
            s2 += w * a[OUT_F + f];
        }
        Wa1[k] = s1 * LOG2E;
        Wa2[k] = s2 * LOG2E;
    }
    for (int idx = gt; idx < IN_F * OUT_F; idx += gridDim.x * blockDim.x) {
        int j    = idx & 7;
        int lane = (idx >> 3) & 63;
        int nb   = (idx >> 9) & 7;
        int kb   = idx >> 12;
        int k = kb * 32 + (lane >> 4) * 8 + j;
        int n = nb * 16 + (lane & 15);
        Wp[idx] = (_Float16)W[k * OUT_F + n];
    }
}

// ---------------------------------------------------------------------------
// Kernel 2 (mega): pack | wh | attr_h fused into ONE launch. The three parts
// are mutually independent (all consume only raw inputs + prep outputs), so
// co-scheduling them lets the compute-ish wh/attr_h waves hide under the
// HBM-bound pack stream instead of serializing three dispatches.
// ---------------------------------------------------------------------------
__global__ __launch_bounds__(256) void mega_kernel(
    const int* __restrict__ feat, unsigned* __restrict__ fmask,
    const float* __restrict__ node_emb, const float* __restrict__ attr_emb,
    const float* __restrict__ Wa1, const float* __restrict__ Wa2,
    float* __restrict__ wh1, float* __restrict__ wh2,
    const _Float16* __restrict__ Wp, _Float16* __restrict__ Vp) {
    int bid = blockIdx.x;
    int wave = threadIdx.x >> 6, lane = threadIdx.x & 63;

    if (bid < PACK_BLOCKS) {
        // ---- pack: feat (0/1 int32, 400 MB) -> fmask bits (12.8 MB), LINEAR ----
        int u = bid * 256 + threadIdx.x;        // u < 3.2M exact
        int row = u / 160;
        int k   = u - row * 160;
        unsigned bits = 0;
        if (k < 156) {                          // attrs k*32 .. k*32+31 all valid
            const int* p = feat + (size_t)row * N_ATTRS + k * 32;
#pragma unroll
            for (int q = 0; q < 8; ++q) {
                i32x4 v = *reinterpret_cast<const i32x4*>(p + q * 4);
                unsigned b = (v.x > 0 ? 1u : 0u) | (v.y > 0 ? 2u : 0u)
                           | (v.z > 0 ? 4u : 0u) | (v.w > 0 ? 8u : 0u);
                bits |= b << (q * 4);
            }
        } else if (k == 156) {                  // attrs 4992..4999
            const int* p = feat + (size_t)row * N_ATTRS + 4992;
#pragma unroll
            for (int q = 0; q < 2; ++q) {
                i32x4 v = *reinterpret_cast<const i32x4*>(p + q * 4);
                unsigned b = (v.x > 0 ? 1u : 0u) | (v.y > 0 ? 2u : 0u)
                           | (v.z > 0 ? 4u : 0u) | (v.w > 0 ? 8u : 0u);
                bits |= b << (q * 4);
            }
        }                                       // k in 157..159: bits = 0
        fmask[u] = bits;
    } else if (bid < PACK_BLOCKS + WH_BLOCKS) {
        // ---- wh: wh1[i] = node_emb[i].Wa1 ; wh2[j] = attr_emb[j].Wa2 ----
        int r = (bid - PACK_BLOCKS) * 4 + wave;   // r in [0, 25000)
        const float* src;
        const float* vec;
        float* dst;
        if (r < N_NODES) {
            src = node_emb + (size_t)r * IN_F; vec = Wa1; dst = wh1 + r;
        } else {
            int r2 = r - N_NODES;
            src = attr_emb + (size_t)r2 * IN_F; vec = Wa2; dst = wh2 + r2;
        }
        float4 ra = *reinterpret_cast<const float4*>(src + lane * 8);
        float4 rb = *reinterpret_cast<const float4*>(src + lane * 8 + 4);
        const float* vp = vec + lane * 8;
        float s = ra.x * vp[0] + ra.y * vp[1] + ra.z * vp[2] + ra.w * vp[3]
                + rb.x * vp[4] + rb.y * vp[5] + rb.z * vp[6] + rb.w * vp[7];
#pragma unroll
        for (int off = 1; off < 64; off <<= 1) s += __shfl_xor(s, off, 64);
        if (lane == 0) *dst = s;
    } else {
        // ---- attr_h: V = attr_emb @ W -> Vp in B-fragment order ----
        int m = lane & 15, quad = lane >> 4;
        int j0 = ((bid - PACK_BLOCKS - WH_BLOCKS) * 4 + wave) * 16;  // < 5120
        int j = j0 + m;
        bool valid = j < N_ATTRS;
        f32x4 acc[8];
#pragma unroll
        for (int nb = 0; nb < 8; ++nb)
#pragma unroll
            for (int t = 0; t < 4; ++t) acc[nb][t] = 0.f;
        const float* arow = attr_emb + (size_t)j * IN_F;
        for (int kk = 0; kk < IN_F / 32; ++kk) {
            f16x8 afrag;
            if (valid) {
                float4 ra = *reinterpret_cast<const float4*>(arow + kk * 32 + quad * 8);
                float4 rb = *reinterpret_cast<const float4*>(arow + kk * 32 + quad * 8 + 4);
                afrag[0] = (_Float16)ra.x; afrag[1] = (_Float16)ra.y;
                afrag[2] = (_Float16)ra.z; afrag[3] = (_Float16)ra.w;
                afrag[4] = (_Float16)rb.x; afrag[5] = (_Float16)rb.y;
                afrag[6] = (_Float16)rb.z; afrag[7] = (_Float16)rb.w;
            } else {
#pragma unroll
                for (int t = 0; t < 8; ++t) afrag[t] = (_Float16)0.f;
            }
            const _Float16* wbase = Wp + (size_t)(kk * 8) * 64 * 8;
#pragma unroll
            for (int nb = 0; nb < 8; ++nb) {
                f16x8 bfrag;
                __builtin_memcpy(&bfrag, wbase + (nb * 64 + lane) * 8, 16);
                acc[nb] = __builtin_amdgcn_mfma_f32_16x16x32_f16(afrag, bfrag, acc[nb], 0, 0, 0);
            }
        }
#pragma unroll
        for (int nb = 0; nb < 8; ++nb) {
#pragma unroll
            for (int reg = 0; reg < 4; ++reg) {
                int jr = j0 + quad * 4 + reg;
                float v = (jr < N_ATTRS) ? acc[nb][reg] : 0.f;  // zero the K padding
                size_t idx = ((size_t)((jr >> 5) * 8 + nb) * 64 +
                              (((jr >> 3) & 3) * 16 + m)) * 8 + (jr & 7);
                Vp[idx] = (_Float16)v;
            }
        }
    }
}

// ---------------------------------------------------------------------------
// Kernel 2b: maxwh2 = max_j wh2[j]; fill wh2 pad with NEGBIG. single block.
// ---------------------------------------------------------------------------
__global__ __launch_bounds__(256) void max_kernel(
    float* __restrict__ wh2, float* __restrict__ maxp) {
    __shared__ float red[4];
    int t = threadIdx.x;
    float m = -1e30f;
    for (int j = t; j < N_ATTRS; j += 256) m = fmaxf(m, wh2[j]);
    for (int j = N_ATTRS + t; j < WH2_PAD; j += 256) wh2[j] = NEGBIG;
#pragma unroll
    for (int off = 1; off < 64; off <<= 1) m = fmaxf(m, __shfl_xor(m, off, 64));
    int wave = t >> 6, lane = t & 63;
    if (lane == 0) red[wave] = m;
    __syncthreads();
    if (t == 0) *maxp = fmaxf(fmaxf(red[0], red[1]), fmaxf(red[2], red[3]));
}

// ---------------------------------------------------------------------------
// Kernel 3 (main): barrier-free, LDS-free main loop over the bitmask.
//  - block = 32 rows, 2 waves (grid 625). Wave w covers ALL 32 rows for
//    ksteps of parity w (dual A-frag chains: rows m and m+16 share every
//    B-frag load -> Vp L2 traffic halves to 625 x 1.28 MB = 800 MB).
//  - fmask read directly from L2 (2 dwords/lane/superstep, linear layout);
//    Vp bfrags + wh2 + fmask all distance-1 double-buffered in named
//    registers (static indices). NO LDS, NO barriers until the epilogue.
//  - epilogue: parity pairs combine via a 16.5 KB LDS overlay, then
//    normalize + ELU + store.
// ---------------------------------------------------------------------------
__global__ __launch_bounds__(128) void attn_kernel(
    const unsigned* __restrict__ fmask, const float* __restrict__ wh1,
    const float* __restrict__ wh2, const float* __restrict__ maxwh2,
    const _Float16* __restrict__ Vp, float* __restrict__ out) {
    __shared__ float accp[32 * 128];
    __shared__ float rsums[32];

    int wave = threadIdx.x >> 6, lane = threadIdx.x & 63;
    int m = lane & 15, quad = lane >> 4;
    int i0 = blockIdx.x * 32;          // 625*32 = 20000 exact
    int half = wave;                   // kstep parity

    float wh1a = wh1[i0 + m];          // rows 0-15 (scaled by log2(e))
    float wh1b = wh1[i0 + 16 + m];     // rows 16-31
    float mx = maxwh2[0];
    float ea = wh1a + mx, eb = wh1b + mx;
    float Mia = fmaxf(ea, 0.2f * ea) - 12.f;   // f16 P in (0, 4096]
    float Mib = fmaxf(eb, 0.2f * eb) - 12.f;

    f32x4 acc[8], acc2[8];
#pragma unroll
    for (int nb = 0; nb < 8; ++nb)
#pragma unroll
        for (int t = 0; t < 4; ++t) { acc[nb][t] = 0.f; acc2[nb][t] = 0.f; }
    float s = 0.f, s2 = 0.f;

    const unsigned* f1p = fmask + (size_t)(i0 + m) * NK;
    const unsigned* f2p = fmask + (size_t)(i0 + 16 + m) * NK;

    // distance-1 double buffers (named -> static register indexing)
    f16x8  bf0[8], bf1[8];
    float4 w0a, w0b, w1a, w1b;
    unsigned f1_0, f2_0, f1_1, f2_1;

    auto loadSS = [&](int ss, f16x8* bf, float4& wa, float4& wb,
                      unsigned& f1, unsigned& f2) {
        int k = 2 * ss + half;
        const _Float16* vb = Vp + (size_t)k * 4096 + lane * 8;
#pragma unroll
        for (int nb = 0; nb < 8; ++nb)
            bf[nb] = *reinterpret_cast<const f16x8*>(vb + nb * 512);
        const float* wp = wh2 + k * 32 + quad * 8;
        wa = *reinterpret_cast<const float4*>(wp);
        wb = *reinterpret_cast<const float4*>(wp + 4);
        f1 = f1p[k];
        f2 = f2p[k];
    };

    auto computeSS = [&](const f16x8* bf, float4 wa, float4 wb,
                         unsigned f1, unsigned f2) {
        unsigned fm1 = f1 >> (quad * 8);
        unsigned fm2 = f2 >> (quad * 8);
        float wv[8] = {wa.x, wa.y, wa.z, wa.w, wb.x, wb.y, wb.z, wb.w};
        f16x8 a1, a2;
#pragma unroll
        for (int t = 0; t < 8; ++t) {
            float e1 = wh1a + wv[t];               // pad attrs: e ~ -1e30
            float l1 = fmaxf(e1, 0.2f * e1);
            float p1 = fast_exp2(l1 - Mia);        // pad: exp2(-huge) = 0
            p1 = (fm1 & (1u << t)) ? p1 : 0.f;
            _Float16 ph1 = (_Float16)p1;
            s += (float)ph1;                       // sum quantized p
            a1[t] = ph1;
            float e2 = wh1b + wv[t];
            float l2 = fmaxf(e2, 0.2f * e2);
            float p2 = fast_exp2(l2 - Mib);
            p2 = (fm2 & (1u << t)) ? p2 : 0.f;
            _Float16 ph2 = (_Float16)p2;
            s2 += (float)ph2;
            a2[t] = ph2;
        }
#pragma unroll
        for (int nb = 0; nb < 8; ++nb)
            acc[nb] = __builtin_amdgcn_mfma_f32_16x16x32_f16(a1, bf[nb], acc[nb], 0, 0, 0);
#pragma unroll
        for (int nb = 0; nb < 8; ++nb)
            acc2[nb] = __builtin_amdgcn_mfma_f32_16x16x32_f16(a2, bf[nb], acc2[nb], 0, 0, 0);
    };

    loadSS(0, bf0, w0a, w0b, f1_0, f2_0);

    for (int ss = 0; ss < NSS; ss += 2) {
        loadSS(ss + 1, bf1, w1a, w1b, f1_1, f2_1);
        computeSS(bf0, w0a, w0b, f1_0, f2_0);
        int kn = (ss + 2 < NSS) ? ss + 2 : NSS - 1;   // redundant tail reload
        loadSS(kn, bf0, w0a, w0b, f1_0, f2_0);
        computeSS(bf1, w1a, w1b, f1_1, f2_1);
    }

    // ---- row sums: combine the 4 quads (each lane -> its row m / m+16) ----
    s += __shfl_xor(s, 16, 64);
    s += __shfl_xor(s, 32, 64);
    s2 += __shfl_xor(s2, 16, 64);
    s2 += __shfl_xor(s2, 32, 64);

    // ---- combine kstep-parity pair via LDS ----
    // C-layout: acc[nb][reg] = P.V[row = quad*4+reg][col = nb*16+m] (chain 1),
    //           acc2 same rows + 16 (chain 2).
    if (wave == 0) {
#pragma unroll
        for (int nb = 0; nb < 8; ++nb)
#pragma unroll
            for (int reg = 0; reg < 4; ++reg) {
                accp[(quad * 4 + reg) * 128 + nb * 16 + m] = acc[nb][reg];
                accp[(16 + quad * 4 + reg) * 128 + nb * 16 + m] = acc2[nb][reg];
            }
        if (lane < 16) { rsums[m] = s; rsums[16 + m] = s2; }
    }
    __syncthreads();
    if (wave == 1) {
#pragma unroll
        for (int nb = 0; nb < 8; ++nb)
#pragma unroll
            for (int reg = 0; reg < 4; ++reg) {
                accp[(quad * 4 + reg) * 128 + nb * 16 + m] += acc[nb][reg];
                accp[(16 + quad * 4 + reg) * 128 + nb * 16 + m] += acc2[nb][reg];
            }
        if (lane < 16) { rsums[m] += s; rsums[16 + m] += s2; }
    }
    __syncthreads();

    // ---- normalize, ELU, store fp32 (32 x 128) ----
    for (int o = threadIdx.x; o < 32 * 128; o += 128) {
        int lr = o >> 7, n = o & 127;
        float v = accp[lr * 128 + n];
        float rs = rsums[lr];
        rs = (rs > 0.f) ? rs : 1.f;
        float h = v / rs;
        float ov = (h > 0.f) ? h : (fast_exp2(h * LOG2E) - 1.f);
        out[(size_t)(i0 + lr) * OUT_F + n] = ov;
    }
}

// ---------------------------------------------------------------------------
extern "C" void kernel_launch(void* const* d_in, const int* in_sizes, int n_in,
                              void* d_out, int out_size, void* d_ws, size_t ws_size,
                              hipStream_t stream) {
    const float* node_emb = (const float*)d_in[0];  // fp32 [20000,512]
    const float* attr_emb = (const float*)d_in[1];  // fp32 [5000,512]
    const int*   feat     = (const int*)d_in[2];    // int32 [20000,5000]
    const float* W        = (const float*)d_in[3];  // fp32 [512,128]
    const float* a        = (const float*)d_in[4];  // fp32 [256,1]
    float*       out      = (float*)d_out;          // fp32 [20000,128]

    char* ws = (char*)d_ws;
    float*    Wa1 = (float*)(ws + 0);          // 512 f32
    float*    Wa2 = (float*)(ws + 4096);       // 512 f32
    float*    wh1 = (float*)(ws + 8192);       // 20000 f32 (ends 88192)
    float*    wh2 = (float*)(ws + 90112);      // 5376 f32 incl. NEGBIG pad (ends 111616)
    float*    mx  = (float*)(ws + 111616);     // 1 f32
    _Float16* Wp  = (_Float16*)(ws + 131072);  // 65536 f16 (ends 262144)
    _Float16* Vp  = (_Float16*)(ws + 262144);  // 5120*128 f16 (ends 1572864)
    unsigned* fmk = (unsigned*)(ws + 2097152); // 20000*160 u32 = 12.8 MB

    prep_kernel<<<64, 256, 0, stream>>>(W, a, Wa1, Wa2, Wp);
    mega_kernel<<<PACK_BLOCKS + WH_BLOCKS + AH_BLOCKS, 256, 0, stream>>>(
        feat, fmk, node_emb, attr_emb, Wa1, Wa2, wh1, wh2, Wp, Vp);
    max_kernel<<<1, 256, 0, stream>>>(wh2, mx);
    attn_kernel<<<625, 128, 0, stream>>>(fmk, wh1, wh2, mx, Vp, out);
}

// Round 6
// 656.927 us; speedup vs baseline: 1.0570x; 1.0570x over previous
//
#include <hip/hip_runtime.h>

// Problem constants
#define N_NODES 20000
#define N_ATTRS 5000
#define IN_F    512
#define OUT_F   128
#define KP      5120          // padded K: 160 ksteps x 32
#define KSTEPS  160
#define NSS     80            // supersteps (2 ksteps each)
#define WH2_PAD 5376          // wh2 allocation incl. pad
#define NEGBIG  -1e30f        // wh2 pad: exp2 underflows to 0 -> self-masking tail
#define LOG2E   1.4426950408889634f

typedef _Float16 f16x8 __attribute__((ext_vector_type(8)));
typedef float    f32x4 __attribute__((ext_vector_type(4)));
typedef int      i32x4 __attribute__((ext_vector_type(4)));

__device__ __forceinline__ float fast_exp2(float x) {
    return __builtin_amdgcn_exp2f(x);
}

// async global->LDS DMA, 16 B per lane. LDS dest = wave-uniform base + lane*16;
// global source is PER-LANE.
__device__ __forceinline__ void async16(void* lds_dst, const void* gsrc) {
    __builtin_amdgcn_global_load_lds(
        (const __attribute__((address_space(1))) unsigned int*)gsrc,
        (__attribute__((address_space(3))) unsigned int*)lds_dst, 16, 0, 0);
}

// monotone float<->uint mapping for atomicMax on float values
__device__ __forceinline__ unsigned fkey(float f) {
    unsigned b = __float_as_uint(f);
    return (b & 0x80000000u) ? ~b : (b | 0x80000000u);
}
__device__ __forceinline__ float funkey(unsigned u) {
    unsigned b = (u & 0x80000000u) ? (u ^ 0x80000000u) : ~u;
    return __uint_as_float(b);
}

// ---------------------------------------------------------------------------
// Kernel 1: Wa1 = W @ a[:128], Wa2 = W @ a[128:], pre-scaled by log2(e);
// repack W into f16 MFMA B-fragment order. Also zero-init the max key.
// ---------------------------------------------------------------------------
__global__ __launch_bounds__(256) void prep_kernel(
    const float* __restrict__ W, const float* __restrict__ a,
    float* __restrict__ Wa1, float* __restrict__ Wa2, _Float16* __restrict__ Wp,
    unsigned* __restrict__ maxu) {
    int gt = blockIdx.x * blockDim.x + threadIdx.x;
    if (gt == 0) maxu[0] = 0u;         // smaller than any real wh2 key
    if (gt < IN_F) {
        int k = gt;
        float s1 = 0.f, s2 = 0.f;
        for (int f = 0; f < OUT_F; ++f) {
            float w = W[k * OUT_F + f];
            s1 += w * a[f];
            s2 += w * a[OUT_F + f];
        }
        Wa1[k] = s1 * LOG2E;
        Wa2[k] = s2 * LOG2E;
    }
    for (int idx = gt; idx < IN_F * OUT_F; idx += gridDim.x * blockDim.x) {
        int j    = idx & 7;
        int lane = (idx >> 3) & 63;
        int nb   = (idx >> 9) & 7;
        int kb   = idx >> 12;
        int k = kb * 32 + (lane >> 4) * 8 + j;
        int n = nb * 16 + (lane & 15);
        Wp[idx] = (_Float16)W[k * OUT_F + n];
    }
}

// ---------------------------------------------------------------------------
// Kernel 2: wh1[i] = node_emb[i].Wa1 ; wh2[j] = attr_emb[j].Wa2.
// Fused extras (replaces the old single-block max_kernel):
//  - attr blocks (bid>=5000) block-reduce their 4 wh2 values and atomicMax
//    a monotone uint key (1250 atomics total, device scope).
//  - block 0 fills the wh2 pad with NEGBIG.
// ---------------------------------------------------------------------------
__global__ __launch_bounds__(256) void wh_kernel(
    const float* __restrict__ node_emb, const float* __restrict__ attr_emb,
    const float* __restrict__ Wa1, const float* __restrict__ Wa2,
    float* __restrict__ wh1, float* __restrict__ wh2,
    unsigned* __restrict__ maxu) {
    __shared__ float red[4];
    int wave = threadIdx.x >> 6, lane = threadIdx.x & 63;
    int r = blockIdx.x * 4 + wave;   // grid = 6250 -> r in [0, 25000)
    const float* src;
    const float* vec;
    float* dst;
    if (r < N_NODES) {
        src = node_emb + (size_t)r * IN_F; vec = Wa1; dst = wh1 + r;
    } else {
        int r2 = r - N_NODES;
        src = attr_emb + (size_t)r2 * IN_F; vec = Wa2; dst = wh2 + r2;
    }
    float4 ra = *reinterpret_cast<const float4*>(src + lane * 8);
    float4 rb = *reinterpret_cast<const float4*>(src + lane * 8 + 4);
    const float* vp = vec + lane * 8;
    float s = ra.x * vp[0] + ra.y * vp[1] + ra.z * vp[2] + ra.w * vp[3]
            + rb.x * vp[4] + rb.y * vp[5] + rb.z * vp[6] + rb.w * vp[7];
#pragma unroll
    for (int off = 1; off < 64; off <<= 1) s += __shfl_xor(s, off, 64);
    if (lane == 0) *dst = s;

    if (blockIdx.x == 0) {           // fill wh2 pad (untouched by other blocks)
        for (int j = N_ATTRS + threadIdx.x; j < WH2_PAD; j += 256) wh2[j] = NEGBIG;
    }
    if (blockIdx.x >= 5000) {        // all 4 waves are attr rows here
        if (lane == 0) red[wave] = s;
        __syncthreads();             // uniform branch across block
        if (threadIdx.x == 0) {
            float m4 = fmaxf(fmaxf(red[0], red[1]), fmaxf(red[2], red[3]));
            atomicMax(maxu, fkey(m4));
        }
    }
}

// ---------------------------------------------------------------------------
// Kernel 3: V = attr_emb @ W  [5120(pad) x 128] f16 in B-fragment order:
// Vp[kk*4096 + nb*512 + lane*8 + jj] = V[kk*32 + (lane>>4)*8 + jj][nb*16 + (lane&15)]
// grid 320 x 64: one wave per block -> spreads over all 256 CUs (the 80x256
// config parked 4 waves on each of only 80 CUs).
// ---------------------------------------------------------------------------
__global__ __launch_bounds__(64) void attr_h_kernel(
    const float* __restrict__ attr_emb, const _Float16* __restrict__ Wp,
    _Float16* __restrict__ Vp) {
    int lane = threadIdx.x & 63;
    int m = lane & 15, quad = lane >> 4;
    int j0 = blockIdx.x * 16;               // grid = 320 -> j0 in [0, 5120)
    int j = j0 + m;
    bool valid = j < N_ATTRS;
    f32x4 acc[8];
#pragma unroll
    for (int nb = 0; nb < 8; ++nb)
#pragma unroll
        for (int t = 0; t < 4; ++t) acc[nb][t] = 0.f;
    const float* arow = attr_emb + (size_t)j * IN_F;
    for (int kk = 0; kk < IN_F / 32; ++kk) {
        f16x8 afrag;
        if (valid) {
            float4 ra = *reinterpret_cast<const float4*>(arow + kk * 32 + quad * 8);
            float4 rb = *reinterpret_cast<const float4*>(arow + kk * 32 + quad * 8 + 4);
            afrag[0] = (_Float16)ra.x; afrag[1] = (_Float16)ra.y;
            afrag[2] = (_Float16)ra.z; afrag[3] = (_Float16)ra.w;
            afrag[4] = (_Float16)rb.x; afrag[5] = (_Float16)rb.y;
            afrag[6] = (_Float16)rb.z; afrag[7] = (_Float16)rb.w;
        } else {
#pragma unroll
            for (int t = 0; t < 8; ++t) afrag[t] = (_Float16)0.f;
        }
        const _Float16* wbase = Wp + (size_t)(kk * 8) * 64 * 8;
#pragma unroll
        for (int nb = 0; nb < 8; ++nb) {
            f16x8 bfrag;
            __builtin_memcpy(&bfrag, wbase + (nb * 64 + lane) * 8, 16);
            acc[nb] = __builtin_amdgcn_mfma_f32_16x16x32_f16(afrag, bfrag, acc[nb], 0, 0, 0);
        }
    }
#pragma unroll
    for (int nb = 0; nb < 8; ++nb) {
#pragma unroll
        for (int reg = 0; reg < 4; ++reg) {
            int jr = j0 + quad * 4 + reg;
            float v = (jr < N_ATTRS) ? acc[nb][reg] : 0.f;  // zero the K padding
            size_t idx = ((size_t)((jr >> 5) * 8 + nb) * 64 +
                          (((jr >> 3) & 3) * 16 + m)) * 8 + (jr & 7);
            Vp[idx] = (_Float16)v;
        }
    }
}

// ---------------------------------------------------------------------------
// Kernel 4 (main), m97-style barrier-enforced pipeline — the proven 651 us
// structure, byte-identical except the max is read via the uint key:
//  - block = 32 rows (grid 625 = 20000/32 exact), 4 waves
//  - wave w: row group (w>>1)*16, kstep parity w&1 (even/odd ksteps)
//  - superstep = 2 ksteps (64 attrs). Per superstep, async global_load_lds:
//      Vp 16 KB (coop, contiguous), feat 8 KB (per-wave, A-frag order:
//      dest = lane*16 -> conflict-free ds_read_b128), wh2 256 B
//    into LDS double buffer; ONE barrier; compute phase reads LDS only.
//  - LDS 48.5 KB -> 3 blocks/CU (12 waves/CU latency cover)
// ---------------------------------------------------------------------------
__global__ __launch_bounds__(256, 3) void attn_kernel(
    const int* __restrict__ feat, const float* __restrict__ wh1,
    const float* __restrict__ wh2, const unsigned* __restrict__ maxu,
    const _Float16* __restrict__ Vp, float* __restrict__ out) {
    __shared__ __align__(16) char lds[49664];   // vbuf 2x16K | fbuf 2x8K | wbuf 2x256
    __shared__ float rsums[32];

    int wave = threadIdx.x >> 6, lane = threadIdx.x & 63;
    int m = lane & 15, quad = lane >> 4;
    int i0 = blockIdx.x * 32;
    int rg = (wave >> 1) * 16;         // row-group base (0 or 16)
    int half = wave & 1;               // kstep parity

    float wh1i = wh1[i0 + rg + m];     // scaled by log2(e)
    float emax = wh1i + funkey(maxu[0]);
    float Mi = fmaxf(emax, 0.2f * emax) - 12.f;   // f16 P in (0, 4096]

    f32x4 acc[8];
#pragma unroll
    for (int nb = 0; nb < 8; ++nb)
#pragma unroll
        for (int t = 0; t < 4; ++t) acc[nb][t] = 0.f;
    float s = 0.f;

    char* vbuf0 = lds;                 // 16384 per buffer
    char* fbuf0 = lds + 32768;         // 8192 per buffer
    char* wbuf0 = lds + 49152;         // 256 per buffer

    const char* featb = (const char*)feat;
    size_t frow_off = (size_t)(i0 + rg + m) * N_ATTRS * 4;   // this lane's row

    // ---- staging for superstep ss into buffer b (async DMA, no waits) ----
    auto stage = [&](int ss, int b) {
        // Vp: 16 KB contiguous, each wave 4 KB
        const char* vsrc = (const char*)Vp + (size_t)ss * 16384 + wave * 4096 + lane * 16;
        char* vdst = vbuf0 + b * 16384 + wave * 4096;
#pragma unroll
        for (int q = 0; q < 4; ++q) async16(vdst + q * 1024, vsrc + q * 1024);
        // feat: this wave's kstep, A-frag order (lane m=row, quad*8 attrs)
        int kbase = (2 * ss + half) * 32;
        char* fdst = fbuf0 + b * 8192 + wave * 2048;
#pragma unroll
        for (int h = 0; h < 2; ++h) {
            int a = kbase + quad * 8 + h * 4;
            a = min(a, N_ATTRS - 4);               // tail clamp (wh2 NEGBIG masks)
            async16(fdst + h * 1024, featb + frow_off + (size_t)a * 4);
        }
        // wh2: 64 floats for the superstep (wave 0, lanes 0-15)
        if (wave == 0 && lane < 16)
            async16(wbuf0 + b * 256, (const char*)(wh2 + ss * 64) + lane * 16);
    };

    stage(0, 0);
    __syncthreads();

    for (int ss = 0; ss < NSS; ++ss) {
        int cur = ss & 1;
        if (ss + 1 < NSS) stage(ss + 1, cur ^ 1);   // flies during compute of ss

        // ---- compute phase: LDS only ----
        char* wb = wbuf0 + cur * 256 + half * 128 + quad * 32;
        float4 wva = *reinterpret_cast<const float4*>(wb);
        float4 wvb = *reinterpret_cast<const float4*>(wb + 16);
        char* fb = fbuf0 + cur * 8192 + wave * 2048 + lane * 16;
        i32x4 fA = *reinterpret_cast<const i32x4*>(fb);
        i32x4 fB = *reinterpret_cast<const i32x4*>(fb + 1024);

        int   fi[8] = {fA.x, fA.y, fA.z, fA.w, fB.x, fB.y, fB.z, fB.w};
        float wv[8] = {wva.x, wva.y, wva.z, wva.w, wvb.x, wvb.y, wvb.z, wvb.w};
        f16x8 afrag;
#pragma unroll
        for (int t = 0; t < 8; ++t) {
            float e = wh1i + wv[t];                // pad attrs: e ~ -1e30
            float l = fmaxf(e, 0.2f * e);
            float p = fast_exp2(l - Mi);           // pad: exp2(-huge) = 0
            p = (fi[t] > 0) ? p : 0.f;
            _Float16 ph = (_Float16)p;
            s += (float)ph;                        // sum quantized p
            afrag[t] = ph;
        }

        char* vb = vbuf0 + cur * 16384 + half * 8192;
#pragma unroll
        for (int nb = 0; nb < 8; ++nb) {
            f16x8 bfrag = *reinterpret_cast<const f16x8*>(vb + nb * 1024 + lane * 16);
            acc[nb] = __builtin_amdgcn_mfma_f32_16x16x32_f16(afrag, bfrag, acc[nb], 0, 0, 0);
        }

        __syncthreads();   // drains s+1 staging; protects buffer swap
    }

    // ---- row sums for this wave's ksteps (rows rg..rg+15) ----
    s += __shfl_xor(s, 16, 64);
    s += __shfl_xor(s, 32, 64);

    // ---- combine kstep-parity pairs; accs overlay on vbuf (16 KB) ----
    float* accp = (float*)lds;   // [group][16][128]
    if (half == 0) {
#pragma unroll
        for (int nb = 0; nb < 8; ++nb)
#pragma unroll
            for (int reg = 0; reg < 4; ++reg)
                accp[(rg + quad * 4 + reg) * 128 + nb * 16 + m] = acc[nb][reg];
        if (lane < 16) rsums[rg + lane] = s;
    }
    __syncthreads();
    if (half == 1) {
#pragma unroll
        for (int nb = 0; nb < 8; ++nb)
#pragma unroll
            for (int reg = 0; reg < 4; ++reg)
                accp[(rg + quad * 4 + reg) * 128 + nb * 16 + m] += acc[nb][reg];
        if (lane < 16) rsums[rg + lane] += s;
    }
    __syncthreads();

    // ---- normalize, ELU, store fp32 (32 x 128) ----
    for (int o = threadIdx.x; o < 32 * 128; o += 256) {
        int lr = o >> 7, n = o & 127;
        float v = accp[lr * 128 + n];
        float rs = rsums[lr];
        rs = (rs > 0.f) ? rs : 1.f;
        float h = v / rs;
        float ov = (h > 0.f) ? h : (fast_exp2(h * LOG2E) - 1.f);
        out[(size_t)(i0 + lr) * OUT_F + n] = ov;
    }
}

// ---------------------------------------------------------------------------
extern "C" void kernel_launch(void* const* d_in, const int* in_sizes, int n_in,
                              void* d_out, int out_size, void* d_ws, size_t ws_size,
                              hipStream_t stream) {
    const float* node_emb = (const float*)d_in[0];  // fp32 [20000,512]
    const float* attr_emb = (const float*)d_in[1];  // fp32 [5000,512]
    const int*   feat     = (const int*)d_in[2];    // int32 [20000,5000]
    const float* W        = (const float*)d_in[3];  // fp32 [512,128]
    const float* a        = (const float*)d_in[4];  // fp32 [256,1]
    float*       out      = (float*)d_out;          // fp32 [20000,128]

    char* ws = (char*)d_ws;
    float*    Wa1 = (float*)(ws + 0);          // 512 f32
    float*    Wa2 = (float*)(ws + 4096);       // 512 f32
    float*    wh1 = (float*)(ws + 8192);       // 20000 f32 (ends 88192)
    float*    wh2 = (float*)(ws + 90112);      // 5376 f32 incl. NEGBIG pad (ends 111616)
    unsigned* mxu = (unsigned*)(ws + 111616);  // 1 u32 (monotone float key)
    _Float16* Wp  = (_Float16*)(ws + 131072);  // 65536 f16 (ends 262144)
    _Float16* Vp  = (_Float16*)(ws + 262144);  // 5120*128 f16 (ends 1572864)

    prep_kernel<<<64, 256, 0, stream>>>(W, a, Wa1, Wa2, Wp, mxu);
    wh_kernel<<<6250, 256, 0, stream>>>(node_emb, attr_emb, Wa1, Wa2, wh1, wh2, mxu);
    attr_h_kernel<<<320, 64, 0, stream>>>(attr_emb, Wp, Vp);
    attn_kernel<<<625, 256, 0, stream>>>(feat, wh1, wh2, mxu, Vp, out);
}